// Round 9
// baseline (227.661 us; speedup 1.0000x reference)
//
#include <hip/hip_runtime.h>

#define DEVI __device__ __forceinline__

typedef __attribute__((ext_vector_type(8))) short bf16x8;
typedef __attribute__((ext_vector_type(4))) float f32x4;
typedef __attribute__((ext_vector_type(16))) float f32x16;

DEVI ushort f2bf(float f) {
  union { float f; unsigned u; } v; v.f = f;
  unsigned u = v.u;
  unsigned r = (u + 0x7FFFu + ((u >> 16) & 1u)) >> 16;
  return (ushort)r;
}
DEVI float bf2f(ushort h) {
  union { unsigned u; float f; } v; v.u = ((unsigned)h) << 16;
  return v.f;
}
DEVI unsigned pkbf(float lo, float hi) {
  unsigned r;
  asm("v_cvt_pk_bf16_f32 %0, %1, %2" : "=v"(r) : "v"(lo), "v"(hi));
  return r;
}
DEVI float exp2v(float x) {
#if __has_builtin(__builtin_amdgcn_exp2f)
  return __builtin_amdgcn_exp2f(x);
#else
  return exp2f(x);
#endif
}

DEVI void gload_lds16(const ushort* g, ushort* l) {
  __builtin_amdgcn_global_load_lds((const __attribute__((address_space(1))) void*)g,
                                   (__attribute__((address_space(3))) void*)l, 16, 0, 0);
}

// bijective XCD swizzle for 2D grids with nwg % 8 == 0
DEVI void xcd_swz(int& bx, int& by) {
  const int nx = gridDim.x;
  const int flat = blockIdx.x + blockIdx.y * nx;
  const int cpx = (nx * gridDim.y) >> 3;
  const int swz = (flat & 7) * cpx + (flat >> 3);
  bx = swz % nx;
  by = swz / nx;
}

// ---------------- cast x: fp32 -> bf16 ----------------
__global__ __launch_bounds__(256) void cast_x(const float* __restrict__ in,
                                              ushort* __restrict__ out, int n4) {
  int i = blockIdx.x * blockDim.x + threadIdx.x;
  if (i < n4) {
    const float4 v = ((const float4*)in)[i];
    uint2 o;
    o.x = (unsigned)f2bf(v.x) | ((unsigned)f2bf(v.y) << 16);
    o.y = (unsigned)f2bf(v.z) | ((unsigned)f2bf(v.w) << 16);
    ((uint2*)out)[i] = o;
  }
}

// ---------------- transpose + cast: W (R x Cc fp32) -> Wt (Cc x R bf16) ----------------
__global__ __launch_bounds__(256) void transpose_cast(const float* __restrict__ in,
                                                      ushort* __restrict__ out,
                                                      int R, int Cc) {
  __shared__ ushort tile[64][65];
  const int t = threadIdx.x;
  const int r0 = blockIdx.y * 64, c0 = blockIdx.x * 64;
  for (int i = 0; i < 16; ++i) {
    int rr = i * 4 + (t >> 6), cc = t & 63;
    tile[rr][cc] = f2bf(in[(size_t)(r0 + rr) * Cc + c0 + cc]);
  }
  __syncthreads();
  for (int i = 0; i < 16; ++i) {
    int cc = i * 4 + (t >> 6), rr = t & 63;
    out[(size_t)(c0 + cc) * R + r0 + rr] = tile[rr][cc];
  }
}

// ---------------- GEMM: A (MxK bf16) @ Bt (NxK bf16)^T, fp32 acc ----------------
// EPI=0: scatter q/k head-major bf16; v group written TRANSPOSED (H,D,N)
// EPI=1: fp32 out + bias
template<int EPI>
__global__ __launch_bounds__(256) void gemm_bt(const ushort* __restrict__ A,
                                               const ushort* __restrict__ Bt,
                                               const float* __restrict__ bias,
                                               void* __restrict__ outp,
                                               int M, int Nn, int K) {
  __shared__ ushort As[128 * 32];
  __shared__ ushort Bs[128 * 32];
  const int tid = threadIdx.x;
  const int w = tid >> 6, l = tid & 63;
  int bx, by;
  xcd_swz(bx, by);
  const int m0 = by * 128, n0 = bx * 128;
  const int wm = (w >> 1) * 64, wn = (w & 1) * 64;
  const int lc = l & 15, lg = l >> 4;

  f32x4 acc[4][4];
  for (int i = 0; i < 4; ++i)
    for (int j = 0; j < 4; ++j) acc[i][j] = (f32x4){0.f, 0.f, 0.f, 0.f};

  const int srow = w * 32 + (l >> 2);
  const int scol = (l & 3) * 8;
  const ushort* gA = A + (size_t)(m0 + srow) * K + scol;
  const ushort* gB = Bt + (size_t)(n0 + srow) * K + scol;

  for (int k0 = 0; k0 < K; k0 += 32) {
    gload_lds16(gA + k0,                 As + (w * 32 + 0) * 32);
    gload_lds16(gA + k0 + (size_t)16 * K, As + (w * 32 + 16) * 32);
    gload_lds16(gB + k0,                 Bs + (w * 32 + 0) * 32);
    gload_lds16(gB + k0 + (size_t)16 * K, Bs + (w * 32 + 16) * 32);
    __syncthreads();
    bf16x8 af[4], bfr[4];
    for (int mi = 0; mi < 4; ++mi)
      af[mi] = *(const bf16x8*)(As + (wm + mi * 16 + lc) * 32 + lg * 8);
    for (int ni = 0; ni < 4; ++ni)
      bfr[ni] = *(const bf16x8*)(Bs + (wn + ni * 16 + lc) * 32 + lg * 8);
    for (int mi = 0; mi < 4; ++mi)
      for (int ni = 0; ni < 4; ++ni)
        acc[mi][ni] = __builtin_amdgcn_mfma_f32_16x16x32_bf16(af[mi], bfr[ni], acc[mi][ni], 0, 0, 0);
    __syncthreads();
  }

  const int lr = lg * 4;
  if constexpr (EPI == 1) {
    float* O = (float*)outp;
    for (int ni = 0; ni < 4; ++ni) {
      int col = n0 + wn + ni * 16 + lc;
      float bv = bias[col];
      for (int mi = 0; mi < 4; ++mi)
        for (int r = 0; r < 4; ++r)
          O[(size_t)(m0 + wm + mi * 16 + lr + r) * Nn + col] = acc[mi][ni][r] + bv;
    }
  } else {
    ushort* O = (ushort*)outp;
    for (int ni = 0; ni < 4; ++ni) {
      int col = n0 + wn + ni * 16 + lc;
      float bv = bias[col];
      int grp = col >> 10;
      int hh = (col >> 6) & 15;
      int dd = col & 63;
      if (grp < 2) {
        size_t base = (size_t)grp * (16 * 4096 * 64) + (size_t)hh * (4096 * 64) + dd;
        for (int mi = 0; mi < 4; ++mi)
          for (int r = 0; r < 4; ++r) {
            int row = m0 + wm + mi * 16 + lr + r;
            O[base + (size_t)row * 64] = f2bf(acc[mi][ni][r] + bv);
          }
      } else {
        // V transposed: Vt (H, D, N) at group offset 2
        size_t base = (size_t)2 * (16 * 4096 * 64) + ((size_t)hh * 64 + dd) * 4096;
        for (int mi = 0; mi < 4; ++mi)
          for (int r = 0; r < 4; ++r) {
            int row = m0 + wm + mi * 16 + lr + r;
            O[base + row] = f2bf(acc[mi][ni][r] + bv);
          }
      }
    }
  }
}

// ---------------- RMSNorm + RoPE on Q,K (in place, bf16 head-major (H,N,D)) ----------------
DEVI void nr_one(ushort* B, const float* g, size_t base, int h, int l16,
                 float c0a, float s0a, float c1a, float s1a, float extra) {
  unsigned u0 = *(const unsigned*)(B + base + 2 * l16);
  unsigned u1 = *(const unsigned*)(B + base + 32 + 2 * l16);
  float t00 = bf2f((ushort)u0), t01 = bf2f((ushort)(u0 >> 16));
  float t10 = bf2f((ushort)u1), t11 = bf2f((ushort)(u1 >> 16));
  float ss = t00 * t00 + t01 * t01 + t10 * t10 + t11 * t11;
  for (int d = 1; d < 16; d <<= 1) ss += __shfl_xor(ss, d, 16);
  float scl = 8.f / fmaxf(sqrtf(ss), 1e-12f);
  scl *= extra;
  float g00 = g[h * 64 + 2 * l16], g01 = g[h * 64 + 2 * l16 + 1];
  float g10 = g[h * 64 + 32 + 2 * l16], g11 = g[h * 64 + 33 + 2 * l16];
  float q00 = t00 * scl * g00, q01 = t01 * scl * g01;
  float q10 = t10 * scl * g10, q11 = t11 * scl * g11;
  float o00 = q00 * c0a - q01 * s0a, o01 = q00 * s0a + q01 * c0a;
  float o10 = q10 * c1a - q11 * s1a, o11 = q10 * s1a + q11 * c1a;
  *(unsigned*)(B + base + 2 * l16) = (unsigned)f2bf(o00) | ((unsigned)f2bf(o01) << 16);
  *(unsigned*)(B + base + 32 + 2 * l16) = (unsigned)f2bf(o10) | ((unsigned)f2bf(o11) << 16);
}

__global__ __launch_bounds__(256) void norm_rope(ushort* __restrict__ Qb,
                                                 ushort* __restrict__ Kb,
                                                 const int* __restrict__ coords,
                                                 const float* __restrict__ gq,
                                                 const float* __restrict__ gk) {
  const int n = blockIdx.x, t = threadIdx.x;
  const int h = t >> 4, l16 = t & 15;
  const float L2_10K_D10 = 1.3287712379549449f; // log2(10000)/10
  float c0a, s0a, c1a, s1a;
  {
    int p = l16;
    int j = p / 10, fi = p - j * 10;
    float freq = exp2f(-(float)fi * L2_10K_D10);
    float ang = (float)coords[n * 3 + j] * freq;
    c0a = cosf(ang); s0a = sinf(ang);
  }
  {
    int p = l16 + 16;
    if (p < 30) {
      int j = p / 10, fi = p - j * 10;
      float freq = exp2f(-(float)fi * L2_10K_D10);
      float ang = (float)coords[n * 3 + j] * freq;
      c1a = cosf(ang); s1a = sinf(ang);
    } else { c1a = 1.f; s1a = 0.f; }
  }
  const size_t base = ((size_t)h * 4096 + n) * 64;
  // fold 1/sqrt(D) * log2(e) into Q so attention scores land in log2 domain
  nr_one(Qb, gq, base, h, l16, c0a, s0a, c1a, s1a, 0.125f * 1.4426950408889634f);
  nr_one(Kb, gk, base, h, l16, c0a, s0a, c1a, s1a, 1.0f);
}

// ---------------- flash attention, swapped-operand 32x32, fixed-shift softmax ----------
// 2-WAVE blocks (128 thr), 64 q-rows/block, grid (64,16)=1024 blocks = 4 blocks/CU:
// barrier couples only 2 waves, and 4 independent blocks/CU fill each other's
// barrier/drain bubbles (R8 residual was sync convoy, not pipe saturation).
// p = exp2(s) directly (no shift: s <= 8*log2e = 11.54 since ||q||=||k||=8 after
// RMS-norm, so p <= 2^11.6 -- safe; softmax normalization makes it exact).
// R5-style 2-buffer LDS pipeline: stage(t+1) -> read(t) -> compute -> vmcnt(0)
// + lgkmcnt(0) + barrier -> swap.
DEVI void attn_step(const bf16x8 (&ck)[8], const bf16x8 (&cv)[8], const bf16x8 (&qf)[4],
                    f32x16& o0, f32x16& o1, f32x4& rs) {
  f32x16 s0, s1;
#pragma unroll
  for (int r = 0; r < 16; ++r) { s0[r] = 0.f; s1[r] = 0.f; }
#pragma unroll
  for (int c = 0; c < 4; ++c) {
    s0 = __builtin_amdgcn_mfma_f32_32x32x16_bf16(ck[c],     qf[c], s0, 0, 0, 0);
    s1 = __builtin_amdgcn_mfma_f32_32x32x16_bf16(ck[c + 4], qf[c], s1, 0, 0, 0);
  }

  // p = exp2(s); lane-local lsum partials (no cross-lane ops here)
#pragma unroll
  for (int r = 0; r < 16; ++r) { s0[r] = exp2v(s0[r]); }
#pragma unroll
  for (int r = 0; r < 16; ++r) { s1[r] = exp2v(s1[r]); }
#pragma unroll
  for (int r = 0; r < 16; r += 4) {
    rs[0] += s0[r] + s1[r];
    rs[1] += s0[r + 1] + s1[r + 1];
    rs[2] += s0[r + 2] + s1[r + 2];
    rs[3] += s0[r + 3] + s1[r + 3];
  }

  // P -> bf16 B-fragments via cvt_pk + permlane32_swap (T12)
  union { unsigned u[4]; bf16x8 v; } pb[4];
  {
    auto r0 = __builtin_amdgcn_permlane32_swap(pkbf(s0[0], s0[1]), pkbf(s0[4], s0[5]), false, false);
    auto r1 = __builtin_amdgcn_permlane32_swap(pkbf(s0[2], s0[3]), pkbf(s0[6], s0[7]), false, false);
    pb[0].u[0] = r0[0]; pb[0].u[1] = r1[0]; pb[0].u[2] = r0[1]; pb[0].u[3] = r1[1];
    auto r2 = __builtin_amdgcn_permlane32_swap(pkbf(s0[8], s0[9]), pkbf(s0[12], s0[13]), false, false);
    auto r3 = __builtin_amdgcn_permlane32_swap(pkbf(s0[10], s0[11]), pkbf(s0[14], s0[15]), false, false);
    pb[1].u[0] = r2[0]; pb[1].u[1] = r3[0]; pb[1].u[2] = r2[1]; pb[1].u[3] = r3[1];
    auto r4 = __builtin_amdgcn_permlane32_swap(pkbf(s1[0], s1[1]), pkbf(s1[4], s1[5]), false, false);
    auto r5 = __builtin_amdgcn_permlane32_swap(pkbf(s1[2], s1[3]), pkbf(s1[6], s1[7]), false, false);
    pb[2].u[0] = r4[0]; pb[2].u[1] = r5[0]; pb[2].u[2] = r4[1]; pb[2].u[3] = r5[1];
    auto r6 = __builtin_amdgcn_permlane32_swap(pkbf(s1[8], s1[9]), pkbf(s1[12], s1[13]), false, false);
    auto r7 = __builtin_amdgcn_permlane32_swap(pkbf(s1[10], s1[11]), pkbf(s1[14], s1[15]), false, false);
    pb[3].u[0] = r6[0]; pb[3].u[1] = r7[0]; pb[3].u[2] = r6[1]; pb[3].u[3] = r7[1];
  }

#pragma unroll
  for (int c = 0; c < 4; ++c) {
    o0 = __builtin_amdgcn_mfma_f32_32x32x16_bf16(cv[c],     pb[c].v, o0, 0, 0, 0);
    o1 = __builtin_amdgcn_mfma_f32_32x32x16_bf16(cv[c + 4], pb[c].v, o1, 0, 0, 0);
  }
}

__global__ __launch_bounds__(128, 2) void attn_fwd(const ushort* __restrict__ Qb,
                                                   const ushort* __restrict__ Kb,
                                                   const ushort* __restrict__ Vt,
                                                   ushort* __restrict__ attnb) {
  __shared__ ushort Ks[2][4096]; // 8 KB per buf: [chunk 0..7][row 0..63][8 elems]
  __shared__ ushort Vs[2][4096];

  // bijective XCD swizzle: 1024 blocks, 8 XCDs -> 128 consecutive work-ids per XCD (2 heads)
  const int flat = blockIdx.x + (blockIdx.y << 6);
  const int swz = (flat & 7) * 128 + (flat >> 3);
  const int bx = swz & 63, h = swz >> 6;

  const int l = threadIdx.x & 63, w = threadIdx.x >> 6; // w in {0,1}
  const int q = l & 31, hi = l >> 5;
  const int q0 = bx * 64 + w * 32;

  // Q B-fragments: col=q (lane&31), k = 8*hi + j, 4 chunks of 16 over D=64
  const ushort* qrow = Qb + ((size_t)h * 4096 + q0 + q) * 64 + hi * 8;
  bf16x8 qf[4];
#pragma unroll
  for (int c = 0; c < 4; ++c) qf[c] = *(const bf16x8*)(qrow + 16 * c);

  f32x16 o0, o1;
#pragma unroll
  for (int r = 0; r < 16; ++r) { o0[r] = 0.f; o1[r] = 0.f; }
  f32x4 rs = (f32x4){0.f, 0.f, 0.f, 0.f};

  // staging source bases (per-lane): lane l stages K row l / V d-row l, chunks 4w..4w+3
  const ushort* gK = Kb + ((size_t)h * 4096 + l) * 64 + 4 * w * 8;
  const ushort* gV = Vt + ((size_t)h * 64 + l) * 4096 + 4 * w * 8;

  ushort* Kc = &Ks[0][0]; ushort* Vc = &Vs[0][0];
  ushort* Kn = &Ks[1][0]; ushort* Vn = &Vs[1][0];

  // stage tile 0 (4 K chunks + 4 V chunks per thread)
#pragma unroll
  for (int i = 0; i < 4; ++i) {
    gload_lds16(gK + 8 * i, Kc + (4 * w + i) * 512);
    gload_lds16(gV + 8 * i, Vc + (4 * w + i) * 512);
  }
  asm volatile("s_waitcnt vmcnt(0)" ::: "memory");
  __builtin_amdgcn_s_barrier();
  __builtin_amdgcn_sched_barrier(0);

  const int lbase = hi * 512 + q * 8;
  for (int t = 0; t < 63; ++t) {
    // stage tile t+1 into the other buffer
    const ushort* sK = gK + (size_t)(t + 1) * 64 * 64;
    const ushort* sV = gV + (t + 1) * 64;
#pragma unroll
    for (int i = 0; i < 4; ++i) {
      gload_lds16(sK + 8 * i, Kn + (4 * w + i) * 512);
      gload_lds16(sV + 8 * i, Vn + (4 * w + i) * 512);
    }

    bf16x8 k[8], v[8];
#pragma unroll
    for (int c = 0; c < 4; ++c) {
      k[c]     = *(const bf16x8*)(Kc + lbase + c * 1024);
      k[c + 4] = *(const bf16x8*)(Kc + lbase + c * 1024 + 256);
      v[c]     = *(const bf16x8*)(Vc + lbase + c * 1024);
      v[c + 4] = *(const bf16x8*)(Vc + lbase + c * 1024 + 256);
    }
    __builtin_amdgcn_s_setprio(1);
    attn_step(k, v, qf, o0, o1, rs);
    __builtin_amdgcn_s_setprio(0);

    asm volatile("s_waitcnt vmcnt(0) lgkmcnt(0)" ::: "memory");
    __builtin_amdgcn_s_barrier();
    __builtin_amdgcn_sched_barrier(0);
    ushort* tp;
    tp = Kc; Kc = Kn; Kn = tp;
    tp = Vc; Vc = Vn; Vn = tp;
  }
  { // last tile
    bf16x8 k[8], v[8];
#pragma unroll
    for (int c = 0; c < 4; ++c) {
      k[c]     = *(const bf16x8*)(Kc + lbase + c * 1024);
      k[c + 4] = *(const bf16x8*)(Kc + lbase + c * 1024 + 256);
      v[c]     = *(const bf16x8*)(Vc + lbase + c * 1024);
      v[c + 4] = *(const bf16x8*)(Vc + lbase + c * 1024 + 256);
    }
    attn_step(k, v, qf, o0, o1, rs);
  }

  // ---- epilogue: lsum reduce (once), then normalize + store ----
  float lsum = (rs[0] + rs[1]) + (rs[2] + rs[3]);
  lsum += __shfl_xor(lsum, 32);
  const float inv = 1.f / lsum;
  ushort* orow = attnb + (size_t)(q0 + q) * 1024 + h * 64;
#pragma unroll
  for (int dt = 0; dt < 2; ++dt) {
    const f32x16& oo = dt ? o1 : o0;
#pragma unroll
    for (int g = 0; g < 4; ++g)
#pragma unroll
      for (int p2 = 0; p2 < 2; ++p2) {
        int r = g * 4 + p2 * 2;
        unsigned pk = pkbf(oo[r] * inv, oo[r + 1] * inv);
        *(unsigned*)(orow + dt * 32 + g * 8 + 4 * hi + p2 * 2) = pk;
      }
  }
}

extern "C" void kernel_launch(void* const* d_in, const int* in_sizes, int n_in,
                              void* d_out, int out_size, void* d_ws, size_t ws_size,
                              hipStream_t stream) {
  const float* x      = (const float*)d_in[0];
  const int*   coords = (const int*)d_in[1];
  const float* W_qkv  = (const float*)d_in[2];
  const float* b_qkv  = (const float*)d_in[3];
  const float* gq     = (const float*)d_in[4];
  const float* gk     = (const float*)d_in[5];
  const float* W_out  = (const float*)d_in[6];
  const float* b_out  = (const float*)d_in[7];
  float* out = (float*)d_out;

  char* ws = (char*)d_ws;
  ushort* xb    = (ushort*)(ws);                       // 8 MiB: x bf16 (4096x1024)
  ushort* wtqkv = (ushort*)(ws + (8u << 20));          // 6 MiB: W_qkv^T bf16 (3072x1024)
  ushort* wtout = (ushort*)(ws + (14u << 20));         // 2 MiB: W_out^T bf16 (1024x1024)
  ushort* Qb    = (ushort*)(ws + (16u << 20));         // 8 MiB (H,N,D)
  ushort* Kb    = (ushort*)(ws + (24u << 20));         // 8 MiB (H,N,D)
  ushort* Vt    = (ushort*)(ws + (32u << 20));         // 8 MiB (H,D,N) -- written by gemm epilogue
  ushort* attnb = (ushort*)(ws + (40u << 20));         // 8 MiB (N,C)  -> total 48 MiB

  cast_x<<<4096, 256, 0, stream>>>(x, xb, 4096 * 1024 / 4);
  transpose_cast<<<dim3(48, 16), 256, 0, stream>>>(W_qkv, wtqkv, 1024, 3072);
  transpose_cast<<<dim3(16, 16), 256, 0, stream>>>(W_out, wtout, 1024, 1024);
  gemm_bt<0><<<dim3(24, 32), 256, 0, stream>>>(xb, wtqkv, b_qkv, (void*)Qb, 4096, 3072, 1024);
  norm_rope<<<4096, 256, 0, stream>>>(Qb, Kb, coords, gq, gk);
  attn_fwd<<<dim3(64, 16), 128, 0, stream>>>(Qb, Kb, Vt, attnb);
  gemm_bt<1><<<dim3(8, 32), 256, 0, stream>>>(attnb, wtout, b_out, (void*)out, 4096, 1024, 1024);
}

// Round 10
// 166.149 us; speedup vs baseline: 1.3702x; 1.3702x over previous
//
#include <hip/hip_runtime.h>

#define DEVI __device__ __forceinline__

typedef __attribute__((ext_vector_type(8))) short bf16x8;
typedef __attribute__((ext_vector_type(4))) float f32x4;
typedef __attribute__((ext_vector_type(16))) float f32x16;

DEVI ushort f2bf(float f) {
  union { float f; unsigned u; } v; v.f = f;
  unsigned u = v.u;
  unsigned r = (u + 0x7FFFu + ((u >> 16) & 1u)) >> 16;
  return (ushort)r;
}
DEVI float bf2f(ushort h) {
  union { unsigned u; float f; } v; v.u = ((unsigned)h) << 16;
  return v.f;
}
DEVI unsigned pkbf(float lo, float hi) {
  unsigned r;
  asm("v_cvt_pk_bf16_f32 %0, %1, %2" : "=v"(r) : "v"(lo), "v"(hi));
  return r;
}
DEVI float exp2v(float x) {
#if __has_builtin(__builtin_amdgcn_exp2f)
  return __builtin_amdgcn_exp2f(x);
#else
  return exp2f(x);
#endif
}

DEVI void gload_lds16(const ushort* g, ushort* l) {
  __builtin_amdgcn_global_load_lds((const __attribute__((address_space(1))) void*)g,
                                   (__attribute__((address_space(3))) void*)l, 16, 0, 0);
}

// bijective XCD swizzle for 2D grids with nwg % 8 == 0
DEVI void xcd_swz(int& bx, int& by) {
  const int nx = gridDim.x;
  const int flat = blockIdx.x + blockIdx.y * nx;
  const int cpx = (nx * gridDim.y) >> 3;
  const int swz = (flat & 7) * cpx + (flat >> 3);
  bx = swz % nx;
  by = swz / nx;
}

// ---------------- prep: cast x -> bf16; transpose+cast W_qkv, W_out ----------------
// 1D grid 5120 blocks: [0,4096) cast x; [4096,4864) W_qkv^T; [4864,5120) W_out^T.
__global__ __launch_bounds__(256) void prep(const float* __restrict__ x,
                                            ushort* __restrict__ xb,
                                            const float* __restrict__ Wq,
                                            ushort* __restrict__ wtq,
                                            const float* __restrict__ Wo,
                                            ushort* __restrict__ wto) {
  __shared__ ushort tile[64][65];
  const int bid = blockIdx.x, t = threadIdx.x;
  if (bid < 4096) {
    int i = bid * 256 + t;
    const float4 v = ((const float4*)x)[i];
    uint2 o;
    o.x = (unsigned)f2bf(v.x) | ((unsigned)f2bf(v.y) << 16);
    o.y = (unsigned)f2bf(v.z) | ((unsigned)f2bf(v.w) << 16);
    ((uint2*)xb)[i] = o;
    return;
  }
  const float* in;
  ushort* out;
  int R, Cc, bx, by;
  if (bid < 4864) {
    in = Wq; out = wtq; R = 1024; Cc = 3072;
    bx = (bid - 4096) % 48; by = (bid - 4096) / 48;
  } else {
    in = Wo; out = wto; R = 1024; Cc = 1024;
    bx = (bid - 4864) % 16; by = (bid - 4864) / 16;
  }
  const int r0 = by * 64, c0 = bx * 64;
  for (int i = 0; i < 16; ++i) {
    int rr = i * 4 + (t >> 6), cc = t & 63;
    tile[rr][cc] = f2bf(in[(size_t)(r0 + rr) * Cc + c0 + cc]);
  }
  __syncthreads();
  for (int i = 0; i < 16; ++i) {
    int cc = i * 4 + (t >> 6), rr = t & 63;
    out[(size_t)(c0 + cc) * R + r0 + rr] = tile[rr][cc];
  }
}

// ---------------- GEMM: A (MxK bf16) @ Bt (NxK bf16)^T, fp32 acc ----------------
// EPI=0: scatter q/k head-major bf16 (RAW, un-normed); v group written TRANSPOSED (H,D,N)
// EPI=1: fp32 out + bias
template<int EPI>
__global__ __launch_bounds__(256) void gemm_bt(const ushort* __restrict__ A,
                                               const ushort* __restrict__ Bt,
                                               const float* __restrict__ bias,
                                               void* __restrict__ outp,
                                               int M, int Nn, int K) {
  __shared__ ushort As[128 * 32];
  __shared__ ushort Bs[128 * 32];
  const int tid = threadIdx.x;
  const int w = tid >> 6, l = tid & 63;
  int bx, by;
  xcd_swz(bx, by);
  const int m0 = by * 128, n0 = bx * 128;
  const int wm = (w >> 1) * 64, wn = (w & 1) * 64;
  const int lc = l & 15, lg = l >> 4;

  f32x4 acc[4][4];
  for (int i = 0; i < 4; ++i)
    for (int j = 0; j < 4; ++j) acc[i][j] = (f32x4){0.f, 0.f, 0.f, 0.f};

  const int srow = w * 32 + (l >> 2);
  const int scol = (l & 3) * 8;
  const ushort* gA = A + (size_t)(m0 + srow) * K + scol;
  const ushort* gB = Bt + (size_t)(n0 + srow) * K + scol;

  for (int k0 = 0; k0 < K; k0 += 32) {
    gload_lds16(gA + k0,                 As + (w * 32 + 0) * 32);
    gload_lds16(gA + k0 + (size_t)16 * K, As + (w * 32 + 16) * 32);
    gload_lds16(gB + k0,                 Bs + (w * 32 + 0) * 32);
    gload_lds16(gB + k0 + (size_t)16 * K, Bs + (w * 32 + 16) * 32);
    __syncthreads();
    bf16x8 af[4], bfr[4];
    for (int mi = 0; mi < 4; ++mi)
      af[mi] = *(const bf16x8*)(As + (wm + mi * 16 + lc) * 32 + lg * 8);
    for (int ni = 0; ni < 4; ++ni)
      bfr[ni] = *(const bf16x8*)(Bs + (wn + ni * 16 + lc) * 32 + lg * 8);
    for (int mi = 0; mi < 4; ++mi)
      for (int ni = 0; ni < 4; ++ni)
        acc[mi][ni] = __builtin_amdgcn_mfma_f32_16x16x32_bf16(af[mi], bfr[ni], acc[mi][ni], 0, 0, 0);
    __syncthreads();
  }

  const int lr = lg * 4;
  if constexpr (EPI == 1) {
    float* O = (float*)outp;
    for (int ni = 0; ni < 4; ++ni) {
      int col = n0 + wn + ni * 16 + lc;
      float bv = bias[col];
      for (int mi = 0; mi < 4; ++mi)
        for (int r = 0; r < 4; ++r)
          O[(size_t)(m0 + wm + mi * 16 + lr + r) * Nn + col] = acc[mi][ni][r] + bv;
    }
  } else {
    ushort* O = (ushort*)outp;
    for (int ni = 0; ni < 4; ++ni) {
      int col = n0 + wn + ni * 16 + lc;
      float bv = bias[col];
      int grp = col >> 10;
      int hh = (col >> 6) & 15;
      int dd = col & 63;
      if (grp < 2) {
        size_t base = (size_t)grp * (16 * 4096 * 64) + (size_t)hh * (4096 * 64) + dd;
        for (int mi = 0; mi < 4; ++mi)
          for (int r = 0; r < 4; ++r) {
            int row = m0 + wm + mi * 16 + lr + r;
            O[base + (size_t)row * 64] = f2bf(acc[mi][ni][r] + bv);
          }
      } else {
        // V transposed: Vt (H, D, N) at group offset 2
        size_t base = (size_t)2 * (16 * 4096 * 64) + ((size_t)hh * 64 + dd) * 4096;
        for (int mi = 0; mi < 4; ++mi)
          for (int r = 0; r < 4; ++r) {
            int row = m0 + wm + mi * 16 + lr + r;
            O[base + row] = f2bf(acc[mi][ni][r] + bv);
          }
      }
    }
  }
}

// ---------------- RMSNorm + RoPE on K only (in place, bf16 head-major (H,N,D)) ----------
__global__ __launch_bounds__(256) void norm_rope_k(ushort* __restrict__ Kb,
                                                   const int* __restrict__ coords,
                                                   const float* __restrict__ gk) {
  const int n = blockIdx.x, t = threadIdx.x;
  const int h = t >> 4, l16 = t & 15;
  const float L2_10K_D10 = 1.3287712379549449f; // log2(10000)/10
  float c0a, s0a, c1a, s1a;
  {
    int p = l16;
    int j = p / 10, fi = p - j * 10;
    float freq = exp2f(-(float)fi * L2_10K_D10);
    float ang = (float)coords[n * 3 + j] * freq;
    c0a = cosf(ang); s0a = sinf(ang);
  }
  {
    int p = l16 + 16;
    if (p < 30) {
      int j = p / 10, fi = p - j * 10;
      float freq = exp2f(-(float)fi * L2_10K_D10);
      float ang = (float)coords[n * 3 + j] * freq;
      c1a = cosf(ang); s1a = sinf(ang);
    } else { c1a = 1.f; s1a = 0.f; }
  }
  const size_t base = ((size_t)h * 4096 + n) * 64;
  unsigned u0 = *(const unsigned*)(Kb + base + 2 * l16);
  unsigned u1 = *(const unsigned*)(Kb + base + 32 + 2 * l16);
  float t00 = bf2f((ushort)u0), t01 = bf2f((ushort)(u0 >> 16));
  float t10 = bf2f((ushort)u1), t11 = bf2f((ushort)(u1 >> 16));
  float ss = t00 * t00 + t01 * t01 + t10 * t10 + t11 * t11;
  for (int d = 1; d < 16; d <<= 1) ss += __shfl_xor(ss, d, 16);
  float scl = 8.f / fmaxf(sqrtf(ss), 1e-12f);
  float g00 = gk[h * 64 + 2 * l16], g01 = gk[h * 64 + 2 * l16 + 1];
  float g10 = gk[h * 64 + 32 + 2 * l16], g11 = gk[h * 64 + 33 + 2 * l16];
  float q00 = t00 * scl * g00, q01 = t01 * scl * g01;
  float q10 = t10 * scl * g10, q11 = t11 * scl * g11;
  float o00 = q00 * c0a - q01 * s0a, o01 = q00 * s0a + q01 * c0a;
  float o10 = q10 * c1a - q11 * s1a, o11 = q10 * s1a + q11 * c1a;
  *(unsigned*)(Kb + base + 2 * l16) = (unsigned)f2bf(o00) | ((unsigned)f2bf(o01) << 16);
  *(unsigned*)(Kb + base + 32 + 2 * l16) = (unsigned)f2bf(o10) | ((unsigned)f2bf(o11) << 16);
}

// ---------------- flash attention (R8 skeleton), Q-norm+RoPE fused in prologue --------
// grid (32, 16) XCD-swizzled, block 256 (4 waves, 32 Q-rows each).
// Q raw from gemm; RMS+RoPE+1/8*log2e applied in-lane here (pairs are in-lane;
// RMS needs one shfl_xor(32) since each lane holds 32 of 64 dims).
// p = exp2(s) directly (s <= 8*log2e bounded since ||q||=||k||=8 post-norm).
// 2-buffer LDS pipeline: stage(t+1) -> read(t) -> compute -> vmcnt(0)+barrier -> swap.
DEVI void attn_step(const bf16x8 (&ck)[8], const bf16x8 (&cv)[8], const bf16x8 (&qf)[4],
                    f32x16& o0, f32x16& o1, f32x4& rs) {
  f32x16 s0, s1;
#pragma unroll
  for (int r = 0; r < 16; ++r) { s0[r] = 0.f; s1[r] = 0.f; }
#pragma unroll
  for (int c = 0; c < 4; ++c) {
    s0 = __builtin_amdgcn_mfma_f32_32x32x16_bf16(ck[c],     qf[c], s0, 0, 0, 0);
    s1 = __builtin_amdgcn_mfma_f32_32x32x16_bf16(ck[c + 4], qf[c], s1, 0, 0, 0);
  }
#pragma unroll
  for (int r = 0; r < 16; ++r) { s0[r] = exp2v(s0[r]); }
#pragma unroll
  for (int r = 0; r < 16; ++r) { s1[r] = exp2v(s1[r]); }
#pragma unroll
  for (int r = 0; r < 16; r += 4) {
    rs[0] += s0[r] + s1[r];
    rs[1] += s0[r + 1] + s1[r + 1];
    rs[2] += s0[r + 2] + s1[r + 2];
    rs[3] += s0[r + 3] + s1[r + 3];
  }
  union { unsigned u[4]; bf16x8 v; } pb[4];
  {
    auto r0 = __builtin_amdgcn_permlane32_swap(pkbf(s0[0], s0[1]), pkbf(s0[4], s0[5]), false, false);
    auto r1 = __builtin_amdgcn_permlane32_swap(pkbf(s0[2], s0[3]), pkbf(s0[6], s0[7]), false, false);
    pb[0].u[0] = r0[0]; pb[0].u[1] = r1[0]; pb[0].u[2] = r0[1]; pb[0].u[3] = r1[1];
    auto r2 = __builtin_amdgcn_permlane32_swap(pkbf(s0[8], s0[9]), pkbf(s0[12], s0[13]), false, false);
    auto r3 = __builtin_amdgcn_permlane32_swap(pkbf(s0[10], s0[11]), pkbf(s0[14], s0[15]), false, false);
    pb[1].u[0] = r2[0]; pb[1].u[1] = r3[0]; pb[1].u[2] = r2[1]; pb[1].u[3] = r3[1];
    auto r4 = __builtin_amdgcn_permlane32_swap(pkbf(s1[0], s1[1]), pkbf(s1[4], s1[5]), false, false);
    auto r5 = __builtin_amdgcn_permlane32_swap(pkbf(s1[2], s1[3]), pkbf(s1[6], s1[7]), false, false);
    pb[2].u[0] = r4[0]; pb[2].u[1] = r5[0]; pb[2].u[2] = r4[1]; pb[2].u[3] = r5[1];
    auto r6 = __builtin_amdgcn_permlane32_swap(pkbf(s1[8], s1[9]), pkbf(s1[12], s1[13]), false, false);
    auto r7 = __builtin_amdgcn_permlane32_swap(pkbf(s1[10], s1[11]), pkbf(s1[14], s1[15]), false, false);
    pb[3].u[0] = r6[0]; pb[3].u[1] = r7[0]; pb[3].u[2] = r6[1]; pb[3].u[3] = r7[1];
  }
#pragma unroll
  for (int c = 0; c < 4; ++c) {
    o0 = __builtin_amdgcn_mfma_f32_32x32x16_bf16(cv[c],     pb[c].v, o0, 0, 0, 0);
    o1 = __builtin_amdgcn_mfma_f32_32x32x16_bf16(cv[c + 4], pb[c].v, o1, 0, 0, 0);
  }
}

__global__ __launch_bounds__(256, 2) void attn_fwd(const ushort* __restrict__ Qb,
                                                   const ushort* __restrict__ Kb,
                                                   const ushort* __restrict__ Vt,
                                                   const int* __restrict__ coords,
                                                   const float* __restrict__ gq,
                                                   ushort* __restrict__ attnb) {
  __shared__ ushort Ks[2][4096]; // 8 KB per buf: [chunk 0..7][row 0..63][8 elems]
  __shared__ ushort Vs[2][4096];

  // bijective XCD swizzle: 512 blocks, 8 XCDs -> 64 consecutive work-ids per XCD (2 heads)
  const int flat = blockIdx.x + (blockIdx.y << 5);
  const int swz = (flat & 7) * 64 + (flat >> 3);
  const int bx = swz & 31, h = swz >> 5;

  const int l = threadIdx.x & 63, w = threadIdx.x >> 6;
  const int q = l & 31, hi = l >> 5;
  const int q0 = bx * 128 + w * 32;
  const int n = q0 + q;

  // ---- Q prologue: load raw q row (32 dims in-lane), RMS-norm + RoPE, repack ----
  bf16x8 qf[4];
  {
    const ushort* qrow = Qb + ((size_t)h * 4096 + n) * 64 + hi * 8;
    float qv[32];
#pragma unroll
    for (int c = 0; c < 4; ++c) {
      bf16x8 rv = *(const bf16x8*)(qrow + 16 * c);
#pragma unroll
      for (int j = 0; j < 8; ++j) qv[c * 8 + j] = bf2f((ushort)rv[j]);
    }
    float ss = 0.f;
#pragma unroll
    for (int i = 0; i < 32; ++i) ss += qv[i] * qv[i];
    ss += __shfl_xor(ss, 32);
    // sqrt(D)/||q|| * 1/sqrt(D) * log2(e)  (scores land in log2 domain)
    const float scl = 8.f / fmaxf(sqrtf(ss), 1e-12f) * 0.125f * 1.4426950408889634f;
    const float L2_10K_D10 = 1.3287712379549449f;
#pragma unroll
    for (int c = 0; c < 4; ++c) {
      union { unsigned u[4]; bf16x8 v; } pk_;
#pragma unroll
      for (int j2 = 0; j2 < 4; ++j2) {
        int p = hi * 4 + 8 * c + j2;
        int dim = hi * 8 + 16 * c + 2 * j2;
        float cs, sn;
        if (p < 30) {
          int j = p / 10, fi = p - 10 * j;
          float ang = (float)coords[n * 3 + j] * exp2f(-(float)fi * L2_10K_D10);
          cs = cosf(ang); sn = sinf(ang);
        } else { cs = 1.f; sn = 0.f; }
        float te = qv[c * 8 + 2 * j2] * scl * gq[h * 64 + dim];
        float to = qv[c * 8 + 2 * j2 + 1] * scl * gq[h * 64 + dim + 1];
        pk_.u[j2] = pkbf(te * cs - to * sn, te * sn + to * cs);
      }
      qf[c] = pk_.v;
    }
  }

  f32x16 o0, o1;
#pragma unroll
  for (int r = 0; r < 16; ++r) { o0[r] = 0.f; o1[r] = 0.f; }
  f32x4 rs = (f32x4){0.f, 0.f, 0.f, 0.f};

  // staging source bases (per-lane): lane l stages K row l / V d-row l, chunk 2w(+i)
  const ushort* gK = Kb + ((size_t)h * 4096 + l) * 64 + 2 * w * 8;
  const ushort* gV = Vt + ((size_t)h * 64 + l) * 4096 + 2 * w * 8;

  ushort* Kc = &Ks[0][0]; ushort* Vc = &Vs[0][0];
  ushort* Kn = &Ks[1][0]; ushort* Vn = &Vs[1][0];

  // stage tile 0
  gload_lds16(gK, Kc + 2 * w * 512);
  gload_lds16(gK + 8, Kc + (2 * w + 1) * 512);
  gload_lds16(gV, Vc + 2 * w * 512);
  gload_lds16(gV + 8, Vc + (2 * w + 1) * 512);
  asm volatile("s_waitcnt vmcnt(0)" ::: "memory");
  __builtin_amdgcn_s_barrier();
  __builtin_amdgcn_sched_barrier(0);

  const int lbase = hi * 512 + q * 8;
  for (int t = 0; t < 63; ++t) {
    const ushort* sK = gK + (size_t)(t + 1) * 64 * 64;
    const ushort* sV = gV + (t + 1) * 64;
    gload_lds16(sK, Kn + 2 * w * 512);
    gload_lds16(sK + 8, Kn + (2 * w + 1) * 512);
    gload_lds16(sV, Vn + 2 * w * 512);
    gload_lds16(sV + 8, Vn + (2 * w + 1) * 512);

    bf16x8 k[8], v[8];
#pragma unroll
    for (int c = 0; c < 4; ++c) {
      k[c]     = *(const bf16x8*)(Kc + lbase + c * 1024);
      k[c + 4] = *(const bf16x8*)(Kc + lbase + c * 1024 + 256);
      v[c]     = *(const bf16x8*)(Vc + lbase + c * 1024);
      v[c + 4] = *(const bf16x8*)(Vc + lbase + c * 1024 + 256);
    }
    __builtin_amdgcn_s_setprio(1);
    attn_step(k, v, qf, o0, o1, rs);
    __builtin_amdgcn_s_setprio(0);

    asm volatile("s_waitcnt vmcnt(0) lgkmcnt(0)" ::: "memory");
    __builtin_amdgcn_s_barrier();
    __builtin_amdgcn_sched_barrier(0);
    ushort* tp;
    tp = Kc; Kc = Kn; Kn = tp;
    tp = Vc; Vc = Vn; Vn = tp;
  }
  { // last tile
    bf16x8 k[8], v[8];
#pragma unroll
    for (int c = 0; c < 4; ++c) {
      k[c]     = *(const bf16x8*)(Kc + lbase + c * 1024);
      k[c + 4] = *(const bf16x8*)(Kc + lbase + c * 1024 + 256);
      v[c]     = *(const bf16x8*)(Vc + lbase + c * 1024);
      v[c + 4] = *(const bf16x8*)(Vc + lbase + c * 1024 + 256);
    }
    attn_step(k, v, qf, o0, o1, rs);
  }

  // ---- epilogue ----
  float lsum = (rs[0] + rs[1]) + (rs[2] + rs[3]);
  lsum += __shfl_xor(lsum, 32);
  const float inv = 1.f / lsum;
  ushort* orow = attnb + (size_t)n * 1024 + h * 64;
#pragma unroll
  for (int dt = 0; dt < 2; ++dt) {
    const f32x16& oo = dt ? o1 : o0;
#pragma unroll
    for (int g = 0; g < 4; ++g)
#pragma unroll
      for (int p2 = 0; p2 < 2; ++p2) {
        int r = g * 4 + p2 * 2;
        unsigned pk = pkbf(oo[r] * inv, oo[r + 1] * inv);
        *(unsigned*)(orow + dt * 32 + g * 8 + 4 * hi + p2 * 2) = pk;
      }
  }
}

extern "C" void kernel_launch(void* const* d_in, const int* in_sizes, int n_in,
                              void* d_out, int out_size, void* d_ws, size_t ws_size,
                              hipStream_t stream) {
  const float* x      = (const float*)d_in[0];
  const int*   coords = (const int*)d_in[1];
  const float* W_qkv  = (const float*)d_in[2];
  const float* b_qkv  = (const float*)d_in[3];
  const float* gq     = (const float*)d_in[4];
  const float* gk     = (const float*)d_in[5];
  const float* W_out  = (const float*)d_in[6];
  const float* b_out  = (const float*)d_in[7];
  float* out = (float*)d_out;

  char* ws = (char*)d_ws;
  ushort* xb    = (ushort*)(ws);                       // 8 MiB: x bf16 (4096x1024)
  ushort* wtqkv = (ushort*)(ws + (8u << 20));          // 6 MiB: W_qkv^T bf16 (3072x1024)
  ushort* wtout = (ushort*)(ws + (14u << 20));         // 2 MiB: W_out^T bf16 (1024x1024)
  ushort* Qb    = (ushort*)(ws + (16u << 20));         // 8 MiB (H,N,D) raw q
  ushort* Kb    = (ushort*)(ws + (24u << 20));         // 8 MiB (H,N,D)
  ushort* Vt    = (ushort*)(ws + (32u << 20));         // 8 MiB (H,D,N) -- written by gemm epilogue
  ushort* attnb = (ushort*)(ws + (40u << 20));         // 8 MiB (N,C)  -> total 48 MiB

  prep<<<5120, 256, 0, stream>>>(x, xb, W_qkv, wtqkv, W_out, wtout);
  gemm_bt<0><<<dim3(24, 32), 256, 0, stream>>>(xb, wtqkv, b_qkv, (void*)Qb, 4096, 3072, 1024);
  norm_rope_k<<<4096, 256, 0, stream>>>(Kb, coords, gk);
  attn_fwd<<<dim3(32, 16), 256, 0, stream>>>(Qb, Kb, Vt, coords, gq, attnb);
  gemm_bt<1><<<dim3(8, 32), 256, 0, stream>>>(attnb, wtout, b_out, (void*)out, 4096, 1024, 1024);
}

// Round 11
// 158.565 us; speedup vs baseline: 1.4358x; 1.0478x over previous
//
#include <hip/hip_runtime.h>

#define DEVI __device__ __forceinline__

typedef __attribute__((ext_vector_type(8))) short bf16x8;
typedef __attribute__((ext_vector_type(4))) float f32x4;
typedef __attribute__((ext_vector_type(16))) float f32x16;

DEVI ushort f2bf(float f) {
  union { float f; unsigned u; } v; v.f = f;
  unsigned u = v.u;
  unsigned r = (u + 0x7FFFu + ((u >> 16) & 1u)) >> 16;
  return (ushort)r;
}
DEVI float bf2f(ushort h) {
  union { unsigned u; float f; } v; v.u = ((unsigned)h) << 16;
  return v.f;
}
DEVI unsigned pkbf(float lo, float hi) {
  unsigned r;
  asm("v_cvt_pk_bf16_f32 %0, %1, %2" : "=v"(r) : "v"(lo), "v"(hi));
  return r;
}
DEVI float exp2v(float x) {
#if __has_builtin(__builtin_amdgcn_exp2f)
  return __builtin_amdgcn_exp2f(x);
#else
  return exp2f(x);
#endif
}

DEVI void gload_lds16(const ushort* g, ushort* l) {
  __builtin_amdgcn_global_load_lds((const __attribute__((address_space(1))) void*)g,
                                   (__attribute__((address_space(3))) void*)l, 16, 0, 0);
}

// bijective XCD swizzle for 2D grids with nwg % 8 == 0
DEVI void xcd_swz(int& bx, int& by) {
  const int nx = gridDim.x;
  const int flat = blockIdx.x + blockIdx.y * nx;
  const int cpx = (nx * gridDim.y) >> 3;
  const int swz = (flat & 7) * cpx + (flat >> 3);
  bx = swz % nx;
  by = swz / nx;
}

// ---------------- prep: cast x -> bf16; transpose+cast W_qkv, W_out ----------------
// 1D grid 5120 blocks: [0,4096) cast x; [4096,4864) W_qkv^T; [4864,5120) W_out^T.
__global__ __launch_bounds__(256) void prep(const float* __restrict__ x,
                                            ushort* __restrict__ xb,
                                            const float* __restrict__ Wq,
                                            ushort* __restrict__ wtq,
                                            const float* __restrict__ Wo,
                                            ushort* __restrict__ wto) {
  __shared__ ushort tile[64][65];
  const int bid = blockIdx.x, t = threadIdx.x;
  if (bid < 4096) {
    int i = bid * 256 + t;
    const float4 v = ((const float4*)x)[i];
    uint2 o;
    o.x = (unsigned)f2bf(v.x) | ((unsigned)f2bf(v.y) << 16);
    o.y = (unsigned)f2bf(v.z) | ((unsigned)f2bf(v.w) << 16);
    ((uint2*)xb)[i] = o;
    return;
  }
  const float* in;
  ushort* out;
  int R, Cc, bx, by;
  if (bid < 4864) {
    in = Wq; out = wtq; R = 1024; Cc = 3072;
    bx = (bid - 4096) % 48; by = (bid - 4096) / 48;
  } else {
    in = Wo; out = wto; R = 1024; Cc = 1024;
    bx = (bid - 4864) % 16; by = (bid - 4864) / 16;
  }
  const int r0 = by * 64, c0 = bx * 64;
  for (int i = 0; i < 16; ++i) {
    int rr = i * 4 + (t >> 6), cc = t & 63;
    tile[rr][cc] = f2bf(in[(size_t)(r0 + rr) * Cc + c0 + cc]);
  }
  __syncthreads();
  for (int i = 0; i < 16; ++i) {
    int cc = i * 4 + (t >> 6), rr = t & 63;
    out[(size_t)(c0 + cc) * R + r0 + rr] = tile[rr][cc];
  }
}

// ---------------- GEMM: A (MxK bf16) @ Bt (NxK bf16)^T, fp32 acc ----------------
// Paired K-steps: two BK=32 sub-tiles staged per sync interval (half the barriers,
// 32 MFMA/barrier-pair). Keeps the 64B-row-stride LDS layout (2-way conflict = free).
// EPI=0: scatter q/k head-major bf16; v group written TRANSPOSED (H,D,N)
// EPI=1: fp32 out + bias
template<int EPI>
__global__ __launch_bounds__(256) void gemm_bt(const ushort* __restrict__ A,
                                               const ushort* __restrict__ Bt,
                                               const float* __restrict__ bias,
                                               void* __restrict__ outp,
                                               int M, int Nn, int K) {
  __shared__ ushort As[2][128 * 32];
  __shared__ ushort Bs[2][128 * 32];
  const int tid = threadIdx.x;
  const int w = tid >> 6, l = tid & 63;
  int bx, by;
  xcd_swz(bx, by);
  const int m0 = by * 128, n0 = bx * 128;
  const int wm = (w >> 1) * 64, wn = (w & 1) * 64;
  const int lc = l & 15, lg = l >> 4;

  f32x4 acc[4][4];
  for (int i = 0; i < 4; ++i)
    for (int j = 0; j < 4; ++j) acc[i][j] = (f32x4){0.f, 0.f, 0.f, 0.f};

  const int srow = w * 32 + (l >> 2);
  const int scol = (l & 3) * 8;
  const ushort* gA = A + (size_t)(m0 + srow) * K + scol;
  const ushort* gB = Bt + (size_t)(n0 + srow) * K + scol;

  for (int k0 = 0; k0 < K; k0 += 64) {
#pragma unroll
    for (int s = 0; s < 2; ++s) {
      gload_lds16(gA + k0 + 32 * s,                  &As[s][(w * 32 + 0) * 32]);
      gload_lds16(gA + k0 + 32 * s + (size_t)16 * K, &As[s][(w * 32 + 16) * 32]);
      gload_lds16(gB + k0 + 32 * s,                  &Bs[s][(w * 32 + 0) * 32]);
      gload_lds16(gB + k0 + 32 * s + (size_t)16 * K, &Bs[s][(w * 32 + 16) * 32]);
    }
    __syncthreads();
#pragma unroll
    for (int s = 0; s < 2; ++s) {
      bf16x8 af[4], bfr[4];
      for (int mi = 0; mi < 4; ++mi)
        af[mi] = *(const bf16x8*)(&As[s][(wm + mi * 16 + lc) * 32 + lg * 8]);
      for (int ni = 0; ni < 4; ++ni)
        bfr[ni] = *(const bf16x8*)(&Bs[s][(wn + ni * 16 + lc) * 32 + lg * 8]);
      for (int mi = 0; mi < 4; ++mi)
        for (int ni = 0; ni < 4; ++ni)
          acc[mi][ni] = __builtin_amdgcn_mfma_f32_16x16x32_bf16(af[mi], bfr[ni], acc[mi][ni], 0, 0, 0);
    }
    __syncthreads();
  }

  const int lr = lg * 4;
  if constexpr (EPI == 1) {
    float* O = (float*)outp;
    for (int ni = 0; ni < 4; ++ni) {
      int col = n0 + wn + ni * 16 + lc;
      float bv = bias[col];
      for (int mi = 0; mi < 4; ++mi)
        for (int r = 0; r < 4; ++r)
          O[(size_t)(m0 + wm + mi * 16 + lr + r) * Nn + col] = acc[mi][ni][r] + bv;
    }
  } else {
    ushort* O = (ushort*)outp;
    for (int ni = 0; ni < 4; ++ni) {
      int col = n0 + wn + ni * 16 + lc;
      float bv = bias[col];
      int grp = col >> 10;
      int hh = (col >> 6) & 15;
      int dd = col & 63;
      if (grp < 2) {
        size_t base = (size_t)grp * (16 * 4096 * 64) + (size_t)hh * (4096 * 64) + dd;
        for (int mi = 0; mi < 4; ++mi)
          for (int r = 0; r < 4; ++r) {
            int row = m0 + wm + mi * 16 + lr + r;
            O[base + (size_t)row * 64] = f2bf(acc[mi][ni][r] + bv);
          }
      } else {
        // V transposed: Vt (H, D, N) at group offset 2
        size_t base = (size_t)2 * (16 * 4096 * 64) + ((size_t)hh * 64 + dd) * 4096;
        for (int mi = 0; mi < 4; ++mi)
          for (int r = 0; r < 4; ++r) {
            int row = m0 + wm + mi * 16 + lr + r;
            O[base + row] = f2bf(acc[mi][ni][r] + bv);
          }
      }
    }
  }
}

// ---------------- RMSNorm + RoPE on Q,K (in place, bf16 head-major (H,N,D)) ----------------
DEVI void nr_one(ushort* B, const float* g, size_t base, int h, int l16,
                 float c0a, float s0a, float c1a, float s1a, float extra) {
  unsigned u0 = *(const unsigned*)(B + base + 2 * l16);
  unsigned u1 = *(const unsigned*)(B + base + 32 + 2 * l16);
  float t00 = bf2f((ushort)u0), t01 = bf2f((ushort)(u0 >> 16));
  float t10 = bf2f((ushort)u1), t11 = bf2f((ushort)(u1 >> 16));
  float ss = t00 * t00 + t01 * t01 + t10 * t10 + t11 * t11;
  for (int d = 1; d < 16; d <<= 1) ss += __shfl_xor(ss, d, 16);
  float scl = 8.f / fmaxf(sqrtf(ss), 1e-12f);
  scl *= extra;
  float g00 = g[h * 64 + 2 * l16], g01 = g[h * 64 + 2 * l16 + 1];
  float g10 = g[h * 64 + 32 + 2 * l16], g11 = g[h * 64 + 33 + 2 * l16];
  float q00 = t00 * scl * g00, q01 = t01 * scl * g01;
  float q10 = t10 * scl * g10, q11 = t11 * scl * g11;
  float o00 = q00 * c0a - q01 * s0a, o01 = q00 * s0a + q01 * c0a;
  float o10 = q10 * c1a - q11 * s1a, o11 = q10 * s1a + q11 * c1a;
  *(unsigned*)(B + base + 2 * l16) = (unsigned)f2bf(o00) | ((unsigned)f2bf(o01) << 16);
  *(unsigned*)(B + base + 32 + 2 * l16) = (unsigned)f2bf(o10) | ((unsigned)f2bf(o11) << 16);
}

__global__ __launch_bounds__(256) void norm_rope(ushort* __restrict__ Qb,
                                                 ushort* __restrict__ Kb,
                                                 const int* __restrict__ coords,
                                                 const float* __restrict__ gq,
                                                 const float* __restrict__ gk) {
  const int n = blockIdx.x, t = threadIdx.x;
  const int h = t >> 4, l16 = t & 15;
  const float L2_10K_D10 = 1.3287712379549449f; // log2(10000)/10
  float c0a, s0a, c1a, s1a;
  {
    int p = l16;
    int j = p / 10, fi = p - j * 10;
    float freq = exp2f(-(float)fi * L2_10K_D10);
    float ang = (float)coords[n * 3 + j] * freq;
    c0a = cosf(ang); s0a = sinf(ang);
  }
  {
    int p = l16 + 16;
    if (p < 30) {
      int j = p / 10, fi = p - j * 10;
      float freq = exp2f(-(float)fi * L2_10K_D10);
      float ang = (float)coords[n * 3 + j] * freq;
      c1a = cosf(ang); s1a = sinf(ang);
    } else { c1a = 1.f; s1a = 0.f; }
  }
  const size_t base = ((size_t)h * 4096 + n) * 64;
  // fold 1/sqrt(D) * log2(e) into Q so attention scores land in log2 domain
  nr_one(Qb, gq, base, h, l16, c0a, s0a, c1a, s1a, 0.125f * 1.4426950408889634f);
  nr_one(Kb, gk, base, h, l16, c0a, s0a, c1a, s1a, 1.0f);
}

// ---------------- flash attention (R8 skeleton), no-shift exp2 softmax ----------------
// grid (32, 16) XCD-swizzled, block 256 (4 waves, 32 Q-rows each).
// Q pre-scaled by log2(e)/8 -> scores in log2 domain; p = exp2(s) directly
// (s <= 8*log2e = 11.54 bounded since ||q||=||k||=8 post-RMS-norm -> p <= 2^11.6,
// safe in fp32/bf16; softmax normalization makes the shift exact).
// 2-buffer LDS pipeline: stage(t+1) -> read(t) -> compute -> vmcnt(0)+barrier -> swap.
DEVI void attn_step(const bf16x8 (&ck)[8], const bf16x8 (&cv)[8], const bf16x8 (&qf)[4],
                    f32x16& o0, f32x16& o1, f32x4& rs) {
  f32x16 s0, s1;
#pragma unroll
  for (int r = 0; r < 16; ++r) { s0[r] = 0.f; s1[r] = 0.f; }
#pragma unroll
  for (int c = 0; c < 4; ++c) {
    s0 = __builtin_amdgcn_mfma_f32_32x32x16_bf16(ck[c],     qf[c], s0, 0, 0, 0);
    s1 = __builtin_amdgcn_mfma_f32_32x32x16_bf16(ck[c + 4], qf[c], s1, 0, 0, 0);
  }
#pragma unroll
  for (int r = 0; r < 16; ++r) { s0[r] = exp2v(s0[r]); }
#pragma unroll
  for (int r = 0; r < 16; ++r) { s1[r] = exp2v(s1[r]); }
#pragma unroll
  for (int r = 0; r < 16; r += 4) {
    rs[0] += s0[r] + s1[r];
    rs[1] += s0[r + 1] + s1[r + 1];
    rs[2] += s0[r + 2] + s1[r + 2];
    rs[3] += s0[r + 3] + s1[r + 3];
  }
  union { unsigned u[4]; bf16x8 v; } pb[4];
  {
    auto r0 = __builtin_amdgcn_permlane32_swap(pkbf(s0[0], s0[1]), pkbf(s0[4], s0[5]), false, false);
    auto r1 = __builtin_amdgcn_permlane32_swap(pkbf(s0[2], s0[3]), pkbf(s0[6], s0[7]), false, false);
    pb[0].u[0] = r0[0]; pb[0].u[1] = r1[0]; pb[0].u[2] = r0[1]; pb[0].u[3] = r1[1];
    auto r2 = __builtin_amdgcn_permlane32_swap(pkbf(s0[8], s0[9]), pkbf(s0[12], s0[13]), false, false);
    auto r3 = __builtin_amdgcn_permlane32_swap(pkbf(s0[10], s0[11]), pkbf(s0[14], s0[15]), false, false);
    pb[1].u[0] = r2[0]; pb[1].u[1] = r3[0]; pb[1].u[2] = r2[1]; pb[1].u[3] = r3[1];
    auto r4 = __builtin_amdgcn_permlane32_swap(pkbf(s1[0], s1[1]), pkbf(s1[4], s1[5]), false, false);
    auto r5 = __builtin_amdgcn_permlane32_swap(pkbf(s1[2], s1[3]), pkbf(s1[6], s1[7]), false, false);
    pb[2].u[0] = r4[0]; pb[2].u[1] = r5[0]; pb[2].u[2] = r4[1]; pb[2].u[3] = r5[1];
    auto r6 = __builtin_amdgcn_permlane32_swap(pkbf(s1[8], s1[9]), pkbf(s1[12], s1[13]), false, false);
    auto r7 = __builtin_amdgcn_permlane32_swap(pkbf(s1[10], s1[11]), pkbf(s1[14], s1[15]), false, false);
    pb[3].u[0] = r6[0]; pb[3].u[1] = r7[0]; pb[3].u[2] = r6[1]; pb[3].u[3] = r7[1];
  }
#pragma unroll
  for (int c = 0; c < 4; ++c) {
    o0 = __builtin_amdgcn_mfma_f32_32x32x16_bf16(cv[c],     pb[c].v, o0, 0, 0, 0);
    o1 = __builtin_amdgcn_mfma_f32_32x32x16_bf16(cv[c + 4], pb[c].v, o1, 0, 0, 0);
  }
}

__global__ __launch_bounds__(256, 2) void attn_fwd(const ushort* __restrict__ Qb,
                                                   const ushort* __restrict__ Kb,
                                                   const ushort* __restrict__ Vt,
                                                   ushort* __restrict__ attnb) {
  __shared__ ushort Ks[2][4096]; // 8 KB per buf: [chunk 0..7][row 0..63][8 elems]
  __shared__ ushort Vs[2][4096];

  // bijective XCD swizzle: 512 blocks, 8 XCDs -> 64 consecutive work-ids per XCD (2 heads)
  const int flat = blockIdx.x + (blockIdx.y << 5);
  const int swz = (flat & 7) * 64 + (flat >> 3);
  const int bx = swz & 31, h = swz >> 5;

  const int l = threadIdx.x & 63, w = threadIdx.x >> 6;
  const int q = l & 31, hi = l >> 5;
  const int q0 = bx * 128 + w * 32;

  // Q B-fragments: col=q (lane&31), k = 8*hi + j, 4 chunks of 16 over D=64
  const ushort* qrow = Qb + ((size_t)h * 4096 + q0 + q) * 64 + hi * 8;
  bf16x8 qf[4];
#pragma unroll
  for (int c = 0; c < 4; ++c) qf[c] = *(const bf16x8*)(qrow + 16 * c);

  f32x16 o0, o1;
#pragma unroll
  for (int r = 0; r < 16; ++r) { o0[r] = 0.f; o1[r] = 0.f; }
  f32x4 rs = (f32x4){0.f, 0.f, 0.f, 0.f};

  // staging source bases (per-lane): lane l stages K row l / V d-row l, chunk 2w(+i)
  const ushort* gK = Kb + ((size_t)h * 4096 + l) * 64 + 2 * w * 8;
  const ushort* gV = Vt + ((size_t)h * 64 + l) * 4096 + 2 * w * 8;

  ushort* Kc = &Ks[0][0]; ushort* Vc = &Vs[0][0];
  ushort* Kn = &Ks[1][0]; ushort* Vn = &Vs[1][0];

  // stage tile 0
  gload_lds16(gK, Kc + 2 * w * 512);
  gload_lds16(gK + 8, Kc + (2 * w + 1) * 512);
  gload_lds16(gV, Vc + 2 * w * 512);
  gload_lds16(gV + 8, Vc + (2 * w + 1) * 512);
  asm volatile("s_waitcnt vmcnt(0)" ::: "memory");
  __builtin_amdgcn_s_barrier();
  __builtin_amdgcn_sched_barrier(0);

  const int lbase = hi * 512 + q * 8;
  for (int t = 0; t < 63; ++t) {
    const ushort* sK = gK + (size_t)(t + 1) * 64 * 64;
    const ushort* sV = gV + (t + 1) * 64;
    gload_lds16(sK, Kn + 2 * w * 512);
    gload_lds16(sK + 8, Kn + (2 * w + 1) * 512);
    gload_lds16(sV, Vn + 2 * w * 512);
    gload_lds16(sV + 8, Vn + (2 * w + 1) * 512);

    bf16x8 k[8], v[8];
#pragma unroll
    for (int c = 0; c < 4; ++c) {
      k[c]     = *(const bf16x8*)(Kc + lbase + c * 1024);
      k[c + 4] = *(const bf16x8*)(Kc + lbase + c * 1024 + 256);
      v[c]     = *(const bf16x8*)(Vc + lbase + c * 1024);
      v[c + 4] = *(const bf16x8*)(Vc + lbase + c * 1024 + 256);
    }
    __builtin_amdgcn_s_setprio(1);
    attn_step(k, v, qf, o0, o1, rs);
    __builtin_amdgcn_s_setprio(0);

    asm volatile("s_waitcnt vmcnt(0) lgkmcnt(0)" ::: "memory");
    __builtin_amdgcn_s_barrier();
    __builtin_amdgcn_sched_barrier(0);
    ushort* tp;
    tp = Kc; Kc = Kn; Kn = tp;
    tp = Vc; Vc = Vn; Vn = tp;
  }
  { // last tile
    bf16x8 k[8], v[8];
#pragma unroll
    for (int c = 0; c < 4; ++c) {
      k[c]     = *(const bf16x8*)(Kc + lbase + c * 1024);
      k[c + 4] = *(const bf16x8*)(Kc + lbase + c * 1024 + 256);
      v[c]     = *(const bf16x8*)(Vc + lbase + c * 1024);
      v[c + 4] = *(const bf16x8*)(Vc + lbase + c * 1024 + 256);
    }
    attn_step(k, v, qf, o0, o1, rs);
  }

  // ---- epilogue: lsum reduce (once), then normalize + store ----
  float lsum = (rs[0] + rs[1]) + (rs[2] + rs[3]);
  lsum += __shfl_xor(lsum, 32);
  const float inv = 1.f / lsum;
  ushort* orow = attnb + (size_t)(q0 + q) * 1024 + h * 64;
#pragma unroll
  for (int dt = 0; dt < 2; ++dt) {
    const f32x16& oo = dt ? o1 : o0;
#pragma unroll
    for (int g = 0; g < 4; ++g)
#pragma unroll
      for (int p2 = 0; p2 < 2; ++p2) {
        int r = g * 4 + p2 * 2;
        unsigned pk = pkbf(oo[r] * inv, oo[r + 1] * inv);
        *(unsigned*)(orow + dt * 32 + g * 8 + 4 * hi + p2 * 2) = pk;
      }
  }
}

extern "C" void kernel_launch(void* const* d_in, const int* in_sizes, int n_in,
                              void* d_out, int out_size, void* d_ws, size_t ws_size,
                              hipStream_t stream) {
  const float* x      = (const float*)d_in[0];
  const int*   coords = (const int*)d_in[1];
  const float* W_qkv  = (const float*)d_in[2];
  const float* b_qkv  = (const float*)d_in[3];
  const float* gq     = (const float*)d_in[4];
  const float* gk     = (const float*)d_in[5];
  const float* W_out  = (const float*)d_in[6];
  const float* b_out  = (const float*)d_in[7];
  float* out = (float*)d_out;

  char* ws = (char*)d_ws;
  ushort* xb    = (ushort*)(ws);                       // 8 MiB: x bf16 (4096x1024)
  ushort* wtqkv = (ushort*)(ws + (8u << 20));          // 6 MiB: W_qkv^T bf16 (3072x1024)
  ushort* wtout = (ushort*)(ws + (14u << 20));         // 2 MiB: W_out^T bf16 (1024x1024)
  ushort* Qb    = (ushort*)(ws + (16u << 20));         // 8 MiB (H,N,D)
  ushort* Kb    = (ushort*)(ws + (24u << 20));         // 8 MiB (H,N,D)
  ushort* Vt    = (ushort*)(ws + (32u << 20));         // 8 MiB (H,D,N) -- written by gemm epilogue
  ushort* attnb = (ushort*)(ws + (40u << 20));         // 8 MiB (N,C)  -> total 48 MiB

  prep<<<5120, 256, 0, stream>>>(x, xb, W_qkv, wtqkv, W_out, wtout);
  gemm_bt<0><<<dim3(24, 32), 256, 0, stream>>>(xb, wtqkv, b_qkv, (void*)Qb, 4096, 3072, 1024);
  norm_rope<<<4096, 256, 0, stream>>>(Qb, Kb, coords, gq, gk);
  attn_fwd<<<dim3(32, 16), 256, 0, stream>>>(Qb, Kb, Vt, attnb);
  gemm_bt<1><<<dim3(8, 32), 256, 0, stream>>>(attnb, wtout, b_out, (void*)out, 4096, 1024, 1024);
}